// Round 2
// baseline (444.993 us; speedup 1.0000x reference)
//
#include <hip/hip_runtime.h>
#include <hip/hip_bf16.h>
#include <stdint.h>

#define T_   8192   // B*S tokens
#define IN_  4096
#define OUT_ 4096
#define GS_  256
#define NG_  16

#define BM 128
#define BN 128
#define BK 64
#define KT (IN_ / BK)   // 64 K-tiles, group = 4 K-tiles

typedef int   v4i __attribute__((ext_vector_type(4)));
typedef float f4  __attribute__((ext_vector_type(4)));

__device__ __forceinline__ void gload16(const void* g, void* l) {
  __builtin_amdgcn_global_load_lds(
      (const __attribute__((address_space(1))) void*)g,
      (__attribute__((address_space(3))) void*)l, 16, 0, 0);
}

// ---------------- per-token dynamic quant (bit-exact vs numpy fp32) --------
__global__ __launch_bounds__(256) void quant_kernel(
    const float* __restrict__ x, int8_t* __restrict__ q,
    float* __restrict__ tscale, float* __restrict__ tzp) {
  const int t = blockIdx.x;
  const int tid = threadIdx.x;
  const float* xr = x + (size_t)t * IN_ + tid * 16;
  float vals[16];
  {
    f4 v0 = *(const f4*)(xr);
    f4 v1 = *(const f4*)(xr + 4);
    f4 v2 = *(const f4*)(xr + 8);
    f4 v3 = *(const f4*)(xr + 12);
#pragma unroll
    for (int i = 0; i < 4; ++i) {
      vals[i] = v0[i]; vals[4 + i] = v1[i]; vals[8 + i] = v2[i]; vals[12 + i] = v3[i];
    }
  }
  float mn = 0.f, mx = 0.f;   // ref clamps: min(.,0), max(.,0)
#pragma unroll
  for (int i = 0; i < 16; ++i) { mn = fminf(mn, vals[i]); mx = fmaxf(mx, vals[i]); }
#pragma unroll
  for (int off = 32; off > 0; off >>= 1) {
    mn = fminf(mn, __shfl_xor(mn, off));
    mx = fmaxf(mx, __shfl_xor(mx, off));
  }
  __shared__ float smn[4], smx[4];
  if ((tid & 63) == 0) { smn[tid >> 6] = mn; smx[tid >> 6] = mx; }
  __syncthreads();
  mn = fminf(fminf(smn[0], smn[1]), fminf(smn[2], smn[3]));
  mx = fmaxf(fmaxf(smx[0], smx[1]), fmaxf(smx[2], smx[3]));

  const float eps = 1.1920928955078125e-7f;  // np.finfo(float32).eps
  float scale = fmaxf((mx - mn) / 255.0f, eps);
  float rmn = mn / scale;
  float rmx = mx / scale;
  float zp0 = ((-128.0f + rmn) + (127.0f + rmx) > 0.0f) ? (-128.0f - rmn)
                                                        : (127.0f - rmx);
  float zp = fminf(fmaxf(rintf(zp0), -128.0f), 127.0f);
  if (tid == 0) { tscale[t] = scale; tzp[t] = zp; }

  v4i packed;
#pragma unroll
  for (int w = 0; w < 4; ++w) {
    int word = 0;
#pragma unroll
    for (int e = 0; e < 4; ++e) {
      float qf = rintf(vals[w * 4 + e] / scale) + zp;
      qf = fminf(fmaxf(qf, -128.0f), 127.0f);
      int qi = (int)qf;
      word |= (qi & 0xff) << (8 * e);
    }
    packed[w] = word;
  }
  *(v4i*)(q + (size_t)t * IN_ + tid * 16) = packed;
}

// ---------------- weight prep: w' = w - z (int8), C1[o] = sum_g s*sum(w') ---
__global__ __launch_bounds__(256) void wprep_kernel(
    const int* __restrict__ w, const float* __restrict__ scales,
    const float* __restrict__ zeros, int8_t* __restrict__ wq,
    float* __restrict__ c1) {
  const int o = blockIdx.x;
  const int tid = threadIdx.x;
  const int g = tid >> 4;  // 16 threads per group of 256 elems
  const int* wr = w + (size_t)o * IN_ + tid * 16;
  const int zi = (int)zeros[o * NG_ + g];
  int ssum = 0;
  v4i packed;
#pragma unroll
  for (int blk = 0; blk < 4; ++blk) {
    v4i ww = *(const v4i*)(wr + blk * 4);
    int word = 0;
#pragma unroll
    for (int e = 0; e < 4; ++e) {
      int wp = ww[e] - zi;   // in [-15,15], fits int8
      ssum += wp;
      word |= (wp & 0xff) << (8 * e);
    }
    packed[blk] = word;
  }
  *(v4i*)(wq + (size_t)o * IN_ + tid * 16) = packed;
  ssum += __shfl_xor(ssum, 1);
  ssum += __shfl_xor(ssum, 2);
  ssum += __shfl_xor(ssum, 4);
  ssum += __shfl_xor(ssum, 8);
  __shared__ float part[NG_];
  if ((tid & 15) == 0) part[g] = scales[o * NG_ + g] * (float)ssum;
  __syncthreads();
  if (tid == 0) {
    float s = 0.f;
#pragma unroll
    for (int i = 0; i < NG_; ++i) s += part[i];
    c1[o] = s;
  }
}

// ---------------- int8 groupwise GEMM, m97 structure ------------------------
__global__ __launch_bounds__(256, 2) void gemm_kernel(
    const int8_t* __restrict__ q, const int8_t* __restrict__ wq,
    const float* __restrict__ scales, const float* __restrict__ tscale,
    const float* __restrict__ tzp, const float* __restrict__ c1,
    float* __restrict__ out) {
  __shared__ int8_t As[BM * BK];   // 8 KB
  __shared__ int8_t Bs[BN * BK];   // 8 KB
  __shared__ float sSc[NG_ * BN];  // 8 KB

  const int tid = threadIdx.x;
  const int lane = tid & 63;
  const int wid = tid >> 6;
  const int R0 = blockIdx.y * BM;
  const int C0 = blockIdx.x * BN;

  // stage this block's scales: sSc[g][col_local]
#pragma unroll
  for (int e = 0; e < 8; ++e) {
    int idx = tid + e * 256;
    int oc = idx >> 4, g = idx & 15;
    sSc[g * BN + oc] = scales[(size_t)(C0 + oc) * NG_ + g];
  }

  const int rowA = tid >> 2;          // 0..63
  const int kb = (tid & 3) * 16;      // byte offset within BK
  const int8_t* gA = q + (size_t)(R0 + rowA) * IN_ + kb;
  const int8_t* gB = wq + (size_t)(C0 + rowA) * IN_ + kb;

  const int wm = (wid >> 1) * 64;
  const int wn = (wid & 1) * 64;
  const int lm = lane & 15;
  const int quad = lane >> 4;

  v4i acci[4][4];
  float accf[4][4][4];
#pragma unroll
  for (int i = 0; i < 4; ++i)
#pragma unroll
    for (int j = 0; j < 4; ++j) {
      acci[i][j] = (v4i){0, 0, 0, 0};
#pragma unroll
      for (int r = 0; r < 4; ++r) accf[i][j][r] = 0.f;
    }

  for (int kt = 0; kt < KT; ++kt) {
    __syncthreads();  // previous tile fully consumed (also covers sSc at kt=0)
    const int koff = kt * BK;
    gload16(gA + koff, &As[tid * 16]);
    gload16(gA + koff + (size_t)64 * IN_, &As[4096 + tid * 16]);
    gload16(gB + koff, &Bs[tid * 16]);
    gload16(gB + koff + (size_t)64 * IN_, &Bs[4096 + tid * 16]);
    __syncthreads();  // compiler drains vmcnt before s_barrier

    v4i af[4], bf[4];
#pragma unroll
    for (int i = 0; i < 4; ++i)
      af[i] = *(const v4i*)&As[(wm + i * 16 + lm) * BK + quad * 16];
#pragma unroll
    for (int j = 0; j < 4; ++j)
      bf[j] = *(const v4i*)&Bs[(wn + j * 16 + lm) * BK + quad * 16];
#pragma unroll
    for (int i = 0; i < 4; ++i)
#pragma unroll
      for (int j = 0; j < 4; ++j)
        acci[i][j] =
            __builtin_amdgcn_mfma_i32_16x16x64_i8(af[i], bf[j], acci[i][j], 0, 0, 0);

    if ((kt & 3) == 3) {  // group boundary: fold int acc into fp32 with s[o,g]
      const int g = kt >> 2;
      float sj[4];
#pragma unroll
      for (int j = 0; j < 4; ++j) sj[j] = sSc[g * BN + wn + j * 16 + lm];
#pragma unroll
      for (int i = 0; i < 4; ++i)
#pragma unroll
        for (int j = 0; j < 4; ++j) {
#pragma unroll
          for (int r = 0; r < 4; ++r)
            accf[i][j][r] += sj[j] * (float)acci[i][j][r];
          acci[i][j] = (v4i){0, 0, 0, 0};
        }
    }
  }

  // epilogue: out = scale_t * (accf - zp_t * C1[o])
  float cj[4];
#pragma unroll
  for (int j = 0; j < 4; ++j) cj[j] = c1[C0 + wn + j * 16 + lm];
#pragma unroll
  for (int i = 0; i < 4; ++i) {
#pragma unroll
    for (int r = 0; r < 4; ++r) {
      const int row = R0 + wm + i * 16 + quad * 4 + r;
      const float tsc = tscale[row];
      const float tz = tzp[row];
#pragma unroll
      for (int j = 0; j < 4; ++j) {
        const int col = C0 + wn + j * 16 + lm;
        out[(size_t)row * OUT_ + col] = tsc * (accf[i][j][r] - tz * cj[j]);
      }
    }
  }
}

extern "C" void kernel_launch(void* const* d_in, const int* in_sizes, int n_in,
                              void* d_out, int out_size, void* d_ws, size_t ws_size,
                              hipStream_t stream) {
  const float* x = (const float*)d_in[0];
  const int* w = (const int*)d_in[1];       // int inputs materialized as int32
  const float* scales = (const float*)d_in[2];
  const float* zeros = (const float*)d_in[3];
  // d_in[4] = group_size scalar (256), baked in at compile time

  uint8_t* ws = (uint8_t*)d_ws;
  int8_t* q = (int8_t*)ws;                                  // 33,554,432 B
  int8_t* wq = (int8_t*)(ws + 33554432);                    // 16,777,216 B
  float* tscale = (float*)(ws + 33554432 + 16777216);       // 32 KB
  float* tzp = (float*)(ws + 33554432 + 16777216 + 32768);  // 32 KB
  float* c1 = (float*)(ws + 33554432 + 16777216 + 65536);   // 16 KB
  float* out = (float*)d_out;

  hipLaunchKernelGGL(quant_kernel, dim3(T_), dim3(256), 0, stream, x, q, tscale, tzp);
  hipLaunchKernelGGL(wprep_kernel, dim3(OUT_), dim3(256), 0, stream, w, scales, zeros, wq, c1);
  hipLaunchKernelGGL(gemm_kernel, dim3(OUT_ / BN, T_ / BM), dim3(256), 0, stream,
                     q, wq, scales, tscale, tzp, c1, out);
}

// Round 3
// 430.140 us; speedup vs baseline: 1.0345x; 1.0345x over previous
//
#include <hip/hip_runtime.h>
#include <hip/hip_bf16.h>
#include <stdint.h>

#define T_   8192   // B*S tokens
#define IN_  4096
#define OUT_ 4096
#define GS_  256
#define NG_  16

#define BM 128
#define BN 128
#define BK 128
#define KT (IN_ / BK)   // 32 K-tiles, group = 2 K-tiles

typedef int   v4i __attribute__((ext_vector_type(4)));
typedef float f4  __attribute__((ext_vector_type(4)));

__device__ __forceinline__ void gload16(const void* g, void* l) {
  __builtin_amdgcn_global_load_lds(
      (const __attribute__((address_space(1))) void*)g,
      (__attribute__((address_space(3))) void*)l, 16, 0, 0);
}

// ---------------- per-token dynamic quant ----------------------------------
// Exact divides only for scale/zp; per-element uses x*(1/scale) (rintf slack
// absorbed by the 0.615 absmax threshold; one LSB of q ~ 0.01 in the output).
__global__ __launch_bounds__(256) void quant_kernel(
    const float* __restrict__ x, int8_t* __restrict__ q,
    float* __restrict__ tscale, float* __restrict__ tzp) {
  const int t = blockIdx.x;
  const int tid = threadIdx.x;
  const float* xr = x + (size_t)t * IN_ + tid * 16;
  float vals[16];
  {
    f4 v0 = *(const f4*)(xr);
    f4 v1 = *(const f4*)(xr + 4);
    f4 v2 = *(const f4*)(xr + 8);
    f4 v3 = *(const f4*)(xr + 12);
#pragma unroll
    for (int i = 0; i < 4; ++i) {
      vals[i] = v0[i]; vals[4 + i] = v1[i]; vals[8 + i] = v2[i]; vals[12 + i] = v3[i];
    }
  }
  float mn = 0.f, mx = 0.f;   // ref clamps: min(.,0), max(.,0)
#pragma unroll
  for (int i = 0; i < 16; ++i) { mn = fminf(mn, vals[i]); mx = fmaxf(mx, vals[i]); }
#pragma unroll
  for (int off = 32; off > 0; off >>= 1) {
    mn = fminf(mn, __shfl_xor(mn, off));
    mx = fmaxf(mx, __shfl_xor(mx, off));
  }
  __shared__ float smn[4], smx[4];
  if ((tid & 63) == 0) { smn[tid >> 6] = mn; smx[tid >> 6] = mx; }
  __syncthreads();
  mn = fminf(fminf(smn[0], smn[1]), fminf(smn[2], smn[3]));
  mx = fmaxf(fmaxf(smx[0], smx[1]), fmaxf(smx[2], smx[3]));

  const float eps = 1.1920928955078125e-7f;  // np.finfo(float32).eps
  float scale = fmaxf((mx - mn) / 255.0f, eps);
  float rmn = mn / scale;   // exact divide (zp must be bit-exact)
  float rmx = mx / scale;
  float zp0 = ((-128.0f + rmn) + (127.0f + rmx) > 0.0f) ? (-128.0f - rmn)
                                                        : (127.0f - rmx);
  float zp = fminf(fmaxf(rintf(zp0), -128.0f), 127.0f);
  if (tid == 0) { tscale[t] = scale; tzp[t] = zp; }

  const float inv = 1.0f / scale;  // one exact divide; 16 multiplies below
  v4i packed;
#pragma unroll
  for (int w = 0; w < 4; ++w) {
    int word = 0;
#pragma unroll
    for (int e = 0; e < 4; ++e) {
      float qf = rintf(vals[w * 4 + e] * inv) + zp;
      qf = fminf(fmaxf(qf, -128.0f), 127.0f);
      int qi = (int)qf;
      word |= (qi & 0xff) << (8 * e);
    }
    packed[w] = word;
  }
  *(v4i*)(q + (size_t)t * IN_ + tid * 16) = packed;
}

// ---------------- weight prep: w' = w - z (int8), C1[o] = sum_g s*sum(w') ---
__global__ __launch_bounds__(256) void wprep_kernel(
    const int* __restrict__ w, const float* __restrict__ scales,
    const float* __restrict__ zeros, int8_t* __restrict__ wq,
    float* __restrict__ c1) {
  const int o = blockIdx.x;
  const int tid = threadIdx.x;
  const int g = tid >> 4;  // 16 threads per group of 256 elems
  const int* wr = w + (size_t)o * IN_ + tid * 16;
  const int zi = (int)zeros[o * NG_ + g];
  int ssum = 0;
  v4i packed;
#pragma unroll
  for (int blk = 0; blk < 4; ++blk) {
    v4i ww = *(const v4i*)(wr + blk * 4);
    int word = 0;
#pragma unroll
    for (int e = 0; e < 4; ++e) {
      int wp = ww[e] - zi;   // in [-15,15], fits int8
      ssum += wp;
      word |= (wp & 0xff) << (8 * e);
    }
    packed[blk] = word;
  }
  *(v4i*)(wq + (size_t)o * IN_ + tid * 16) = packed;
  ssum += __shfl_xor(ssum, 1);
  ssum += __shfl_xor(ssum, 2);
  ssum += __shfl_xor(ssum, 4);
  ssum += __shfl_xor(ssum, 8);
  __shared__ float part[NG_];
  if ((tid & 15) == 0) part[g] = scales[o * NG_ + g] * (float)ssum;
  __syncthreads();
  if (tid == 0) {
    float s = 0.f;
#pragma unroll
    for (int i = 0; i < NG_; ++i) s += part[i];
    c1[o] = s;
  }
}

// ---------------- int8 groupwise GEMM, BK=128, XOR-swizzled LDS -------------
// LDS layout: row-major [128][BK], but 16-B chunk q of row r is stored at
// physical chunk p = q ^ (r&7).  Staging swizzles the GLOBAL column instead
// (global_load_lds requires contiguous lane->LDS).  Fragment reads then hit
// 8 distinct bank-quads per 16 lanes -> 2-way conflicts only (free, m136).
__global__ __launch_bounds__(256, 2) void gemm_kernel(
    const int8_t* __restrict__ q, const int8_t* __restrict__ wq,
    const float* __restrict__ scales, const float* __restrict__ tscale,
    const float* __restrict__ tzp, const float* __restrict__ c1,
    float* __restrict__ out) {
  __shared__ int8_t As[BM * BK];   // 16 KB
  __shared__ int8_t Bs[BN * BK];   // 16 KB
  __shared__ float sSc[NG_ * BN];  // 8 KB

  const int tid = threadIdx.x;
  const int lane = tid & 63;
  const int wid = tid >> 6;
  const int R0 = blockIdx.y * BM;
  const int C0 = blockIdx.x * BN;

  // stage this block's scales: sSc[g][col_local]
#pragma unroll
  for (int e = 0; e < 8; ++e) {
    int idx = tid + e * 256;
    int oc = idx >> 4, g = idx & 15;
    sSc[g * BN + oc] = scales[(size_t)(C0 + oc) * NG_ + g];
  }

  // staging: thread covers 16 B; row = tid>>3 (+32 per i), physical chunk tid&7
  const int rA = tid >> 3;                       // 0..31
  const int cswz = ((tid & 7) ^ (rA & 7)) * 16;  // swizzled global column
  const int8_t* gA = q + (size_t)(R0 + rA) * IN_ + cswz;
  const int8_t* gB = wq + (size_t)(C0 + rA) * IN_ + cswz;

  const int wm = (wid >> 1) * 64;
  const int wn = (wid & 1) * 64;
  const int lm = lane & 15;
  const int quad = lane >> 4;
  // fragment read offsets: logical chunk (ks*4+quad) ^ (lm&7)
  const int o0 = ((quad ^ (lm & 7)) * 16);       // ks=0
  const int aRow = (wm + lm) * BK;
  const int bRow = (wn + lm) * BK;

  v4i acci[4][4];
  float accf[4][4][4];
#pragma unroll
  for (int i = 0; i < 4; ++i)
#pragma unroll
    for (int j = 0; j < 4; ++j) {
      acci[i][j] = (v4i){0, 0, 0, 0};
#pragma unroll
      for (int r = 0; r < 4; ++r) accf[i][j][r] = 0.f;
    }

  for (int kt = 0; kt < KT; ++kt) {
    __syncthreads();  // previous tile fully consumed (also covers sSc at kt=0)
    const int koff = kt * BK;
#pragma unroll
    for (int i = 0; i < 4; ++i) {
      gload16(gA + koff + (size_t)(i * 32) * IN_, &As[i * 4096 + tid * 16]);
      gload16(gB + koff + (size_t)(i * 32) * IN_, &Bs[i * 4096 + tid * 16]);
    }
    __syncthreads();  // compiler drains vmcnt before s_barrier

#pragma unroll
    for (int ks = 0; ks < 2; ++ks) {
      const int co = o0 ^ (ks * 64);   // chunk offset for this k-step
      v4i af[4], bf[4];
#pragma unroll
      for (int i = 0; i < 4; ++i)
        af[i] = *(const v4i*)&As[aRow + i * (16 * BK) + co];
#pragma unroll
      for (int j = 0; j < 4; ++j)
        bf[j] = *(const v4i*)&Bs[bRow + j * (16 * BK) + co];
#pragma unroll
      for (int i = 0; i < 4; ++i)
#pragma unroll
        for (int j = 0; j < 4; ++j)
          acci[i][j] =
              __builtin_amdgcn_mfma_i32_16x16x64_i8(af[i], bf[j], acci[i][j], 0, 0, 0);
    }

    if (kt & 1) {  // group boundary (group = 2 kt): fold int acc into fp32
      const int g = kt >> 1;
      float sj[4];
#pragma unroll
      for (int j = 0; j < 4; ++j) sj[j] = sSc[g * BN + wn + j * 16 + lm];
#pragma unroll
      for (int i = 0; i < 4; ++i)
#pragma unroll
        for (int j = 0; j < 4; ++j) {
#pragma unroll
          for (int r = 0; r < 4; ++r)
            accf[i][j][r] += sj[j] * (float)acci[i][j][r];
          acci[i][j] = (v4i){0, 0, 0, 0};
        }
    }
  }

  // epilogue: out = scale_t * (accf - zp_t * C1[o])
  float cj[4];
#pragma unroll
  for (int j = 0; j < 4; ++j) cj[j] = c1[C0 + wn + j * 16 + lm];
#pragma unroll
  for (int i = 0; i < 4; ++i) {
#pragma unroll
    for (int r = 0; r < 4; ++r) {
      const int row = R0 + wm + i * 16 + quad * 4 + r;
      const float tsc = tscale[row];
      const float tz = tzp[row];
#pragma unroll
      for (int j = 0; j < 4; ++j) {
        const int col = C0 + wn + j * 16 + lm;
        out[(size_t)row * OUT_ + col] = tsc * (accf[i][j][r] - tz * cj[j]);
      }
    }
  }
}

extern "C" void kernel_launch(void* const* d_in, const int* in_sizes, int n_in,
                              void* d_out, int out_size, void* d_ws, size_t ws_size,
                              hipStream_t stream) {
  const float* x = (const float*)d_in[0];
  const int* w = (const int*)d_in[1];       // int inputs materialized as int32
  const float* scales = (const float*)d_in[2];
  const float* zeros = (const float*)d_in[3];
  // d_in[4] = group_size scalar (256), baked in at compile time

  uint8_t* ws = (uint8_t*)d_ws;
  int8_t* q = (int8_t*)ws;                                  // 33,554,432 B
  int8_t* wq = (int8_t*)(ws + 33554432);                    // 16,777,216 B
  float* tscale = (float*)(ws + 33554432 + 16777216);       // 32 KB
  float* tzp = (float*)(ws + 33554432 + 16777216 + 32768);  // 32 KB
  float* c1 = (float*)(ws + 33554432 + 16777216 + 65536);   // 16 KB
  float* out = (float*)d_out;

  hipLaunchKernelGGL(quant_kernel, dim3(T_), dim3(256), 0, stream, x, q, tscale, tzp);
  hipLaunchKernelGGL(wprep_kernel, dim3(OUT_), dim3(256), 0, stream, w, scales, zeros, wq, c1);
  hipLaunchKernelGGL(gemm_kernel, dim3(OUT_ / BN, T_ / BM), dim3(256), 0, stream,
                     q, wq, scales, tscale, tzp, c1, out);
}